// Round 3
// baseline (3804.555 us; speedup 1.0000x reference)
//
#include <hip/hip_runtime.h>
#include <hip/hip_fp16.h>

#define B_ 64
#define L_ 128
#define E_ 300
#define HD_ 200
#define H_ 400
#define S_ 50
#define START_ 48
#define END_ 49
#define NG_ 1600
#define BL_ 8192

// ---- ws layout (bytes) ----
// OFF_SH region is time-shared: w16q (prep->lstm), then feats (feat->crf).
#define OFF_XG   0ull                         // bf16 [8192][1600]  26,214,400
#define OFF_LSTM (OFF_XG + 26214400ull)       // f32  [8192][400]   13,107,200
#define OFF_SH   (OFF_LSTM + 13107200ull)     // max(w16q 640,000 ; feats 1,638,400)
#define OFF_WTT  (OFF_SH + 1638400ull)        // f32  [400][50]     80,000
#define OFF_ACC  (OFF_WTT + 80000ull)         // f32  [1]

typedef __attribute__((ext_vector_type(8))) short short8;
typedef __attribute__((ext_vector_type(4))) float f32x4;

__device__ __forceinline__ unsigned short f32_to_bf16(float f) {
    unsigned u = __float_as_uint(f);
    unsigned r = u + 0x7fffu + ((u >> 16) & 1u);
    return (unsigned short)(r >> 16);
}
__device__ __forceinline__ float bf16_to_f32(unsigned short s) {
    return __uint_as_float(((unsigned)s) << 16);
}
__device__ __forceinline__ unsigned packh2(float a, float b) {
    return (unsigned)__half_as_ushort(__float2half(a)) |
           ((unsigned)__half_as_ushort(__float2half(b)) << 16);
}
__device__ __forceinline__ float hlo(unsigned u) {
    return __half2float(__ushort_as_half((unsigned short)(u & 0xffffu)));
}
__device__ __forceinline__ float hhi(unsigned u) {
    return __half2float(__ushort_as_half((unsigned short)(u >> 16)));
}

// ---------------- prep: w_hh (both dirs) -> f16x2 uint4 [dir][kq(25)][row(800)];
// W_tag transpose; acc=0.  word(kq,row) packs w[row][8kq..8kq+7].
__global__ void prep_kernel(const float* __restrict__ whh_f, const float* __restrict__ whh_b,
                            const float* __restrict__ wtag, float* __restrict__ wtagT,
                            uint4* __restrict__ w16q, float* __restrict__ acc) {
    int g = blockIdx.x * 256 + threadIdx.x;
    if (g < 40000) {
        int dir = g / 20000;
        int r = g % 20000;
        int kq = r / 800;
        int row = r % 800;
        const float* w = dir ? whh_b : whh_f;
        const float* src = w + row * HD_ + 8 * kq;
        uint4 o;
        o.x = packh2(src[0], src[1]);
        o.y = packh2(src[2], src[3]);
        o.z = packh2(src[4], src[5]);
        o.w = packh2(src[6], src[7]);
        w16q[g] = o;
    }
    if (g < 20000) {
        int k = g / S_, s = g % S_;
        wtagT[g] = wtag[s * H_ + k];
    }
    if (g == 0) acc[0] = 0.f;
}

// ---------------- xg GEMM (MFMA bf16): unchanged from round 2 (passed).
__global__ __launch_bounds__(256) void xg_gemm(const int* __restrict__ words,
                                               const float* __restrict__ emb,
                                               const float* __restrict__ wihf,
                                               const float* __restrict__ wihb,
                                               const float* __restrict__ bfc,
                                               const float* __restrict__ bbc,
                                               unsigned short* __restrict__ xg) {
    __shared__ unsigned short As[128 * 40];
    __shared__ unsigned short Bs[128 * 40];
    __shared__ int wlds[128];
    int tid = threadIdx.x;
    int bm = blockIdx.y * 128;
    int bn = blockIdx.x * 128;
    if (tid < 128) wlds[tid] = words[bm + tid];
    __syncthreads();

    int srow = tid >> 1;
    int ks = (tid & 1) * 16;
    int lane = tid & 63;
    int wave = tid >> 6;
    int r16 = lane & 15;
    int kh = lane >> 4;

    f32x4 acc[2][8];
#pragma unroll
    for (int mi = 0; mi < 2; ++mi)
#pragma unroll
        for (int ni = 0; ni < 8; ++ni) acc[mi][ni] = (f32x4){0.f, 0.f, 0.f, 0.f};

    const float* arow = emb + (long)wlds[srow] * E_;
    int gB = bn + srow;
    const float* brow = (gB < 800) ? (wihf + (long)gB * E_) : (wihb + (long)(gB - 800) * E_);
    bool bvalid = gB < NG_;

    for (int k0 = 0; k0 < 320; k0 += 32) {
#pragma unroll
        for (int j = 0; j < 4; ++j) {
            int k = k0 + ks + 4 * j;
            float4 va = (k < E_) ? *(const float4*)(arow + k) : make_float4(0.f, 0.f, 0.f, 0.f);
            unsigned p0 = (unsigned)f32_to_bf16(va.x) | ((unsigned)f32_to_bf16(va.y) << 16);
            unsigned p1 = (unsigned)f32_to_bf16(va.z) | ((unsigned)f32_to_bf16(va.w) << 16);
            *(uint2*)&As[srow * 40 + ks + 4 * j] = make_uint2(p0, p1);
            float4 vb = (bvalid && k < E_) ? *(const float4*)(brow + k) : make_float4(0.f, 0.f, 0.f, 0.f);
            unsigned q0 = (unsigned)f32_to_bf16(vb.x) | ((unsigned)f32_to_bf16(vb.y) << 16);
            unsigned q1 = (unsigned)f32_to_bf16(vb.z) | ((unsigned)f32_to_bf16(vb.w) << 16);
            *(uint2*)&Bs[srow * 40 + ks + 4 * j] = make_uint2(q0, q1);
        }
        __syncthreads();
        short8 af[2], bfv[8];
#pragma unroll
        for (int mi = 0; mi < 2; ++mi)
            af[mi] = *(const short8*)&As[(wave * 32 + mi * 16 + r16) * 40 + kh * 8];
#pragma unroll
        for (int ni = 0; ni < 8; ++ni)
            bfv[ni] = *(const short8*)&Bs[(ni * 16 + r16) * 40 + kh * 8];
#pragma unroll
        for (int mi = 0; mi < 2; ++mi)
#pragma unroll
            for (int ni = 0; ni < 8; ++ni)
                acc[mi][ni] = __builtin_amdgcn_mfma_f32_16x16x32_bf16(af[mi], bfv[ni], acc[mi][ni], 0, 0, 0);
        __syncthreads();
    }
#pragma unroll
    for (int ni = 0; ni < 8; ++ni) {
        int g = bn + ni * 16 + r16;
        if (g < NG_) {
            float bias = (g < 800) ? bfc[g] : bbc[g - 800];
#pragma unroll
            for (int mi = 0; mi < 2; ++mi) {
#pragma unroll
                for (int r = 0; r < 4; ++r) {
                    int row = bm + wave * 32 + mi * 16 + kh * 4 + r;
                    xg[(long)row * NG_ + g] = f32_to_bf16(acc[mi][ni][r] + bias);
                }
            }
        }
    }
}

// ---------------- LSTM recurrence: block=(dir,batch), 512 thr (8 waves), 400 active.
// Thread t<400 owns gate rows {t, t+400}; its 400 f16 weights live in 2x25 uint4 REGISTERS
// (200 VGPR; 8-wave block => 256-VGPR cap, fits — round-2 spilled at the 128 cap).
// Rows: t<200 -> (i[ko=t], g~[ko=t]);  200<=t<400 -> (f[ko=t-200], o[ko=t-200]).
__global__ __launch_bounds__(512) void lstm_rec(const unsigned short* __restrict__ xg,
                                                const uint4* __restrict__ w16q,
                                                float* __restrict__ lstm_out) {
    __shared__ __align__(16) float h[HD_];
    __shared__ float a_lds[2 * HD_];   // [0:200)=sig(f), [200:400)=sig(o)
    int tid = threadIdx.x;
    int dir = blockIdx.x >> 6;
    int b = blockIdx.x & 63;
    bool act = tid < 400;

    uint4 wA[25], wB[25];
    const uint4* wp = w16q + dir * 20000;
    if (act) {
#pragma unroll
        for (int kq = 0; kq < 25; ++kq) {
            wA[kq] = wp[kq * 800 + tid];
            wB[kq] = wp[kq * 800 + tid + 400];
        }
    }
    if (tid < HD_) h[tid] = 0.f;
    float c = 0.f;
    __syncthreads();
    const float4* h4 = (const float4*)h;
    const unsigned short* xbase = xg + (long)b * L_ * NG_ + dir * 800;

    for (int step = 0; step < L_; ++step) {
        int t = dir ? (L_ - 1 - step) : step;
        float pa = 0.f, pb = 0.f;
        if (act) {
            const unsigned short* xr = xbase + (long)t * NG_;
            float sa0 = bf16_to_f32(xr[tid]), sa1 = 0.f;
            float sb0 = bf16_to_f32(xr[tid + 400]), sb1 = 0.f;
#pragma unroll
            for (int kq = 0; kq < 25; ++kq) {
                float4 ha = h4[2 * kq];
                float4 hb = h4[2 * kq + 1];
                uint4 a = wA[kq];
                uint4 w2 = wB[kq];
                sa0 = fmaf(hlo(a.x), ha.x, sa0); sa1 = fmaf(hhi(a.x), ha.y, sa1);
                sa0 = fmaf(hlo(a.y), ha.z, sa0); sa1 = fmaf(hhi(a.y), ha.w, sa1);
                sa0 = fmaf(hlo(a.z), hb.x, sa0); sa1 = fmaf(hhi(a.z), hb.y, sa1);
                sa0 = fmaf(hlo(a.w), hb.z, sa0); sa1 = fmaf(hhi(a.w), hb.w, sa1);
                sb0 = fmaf(hlo(w2.x), ha.x, sb0); sb1 = fmaf(hhi(w2.x), ha.y, sb1);
                sb0 = fmaf(hlo(w2.y), ha.z, sb0); sb1 = fmaf(hhi(w2.y), ha.w, sb1);
                sb0 = fmaf(hlo(w2.z), hb.x, sb0); sb1 = fmaf(hhi(w2.z), hb.y, sb1);
                sb0 = fmaf(hlo(w2.w), hb.z, sb0); sb1 = fmaf(hhi(w2.w), hb.w, sb1);
            }
            pa = sa0 + sa1;
            pb = sb0 + sb1;
            if (tid >= 200) {
                // f and o gates: publish sigmoids
                a_lds[tid - 200] = 1.f / (1.f + __expf(-pa));   // sig(f) at [ko]
                a_lds[tid]       = 1.f / (1.f + __expf(-pb));   // sig(o) at [200+ko]
            }
        }
        __syncthreads();
        if (tid < HD_) {
            float ig = 1.f / (1.f + __expf(-pa));
            float e2 = __expf(-2.f * pb);
            float gg = 2.f / (1.f + e2) - 1.f;                  // tanh(g~)
            float fg = a_lds[tid];
            float og = a_lds[200 + tid];
            c = fg * c + ig * gg;
            float ec = __expf(-2.f * c);
            float hn = og * (2.f / (1.f + ec) - 1.f);
            h[tid] = hn;
            lstm_out[((long)(b * L_ + t)) * H_ + dir * HD_ + tid] = hn;
        }
        __syncthreads();
    }
}

// ---------------- features = lstm_out @ W_tag^T + b_tag
__global__ __launch_bounds__(256) void feat_kernel(const float* __restrict__ lstm_out,
                                                   const float* __restrict__ wtagT,
                                                   const float* __restrict__ btag,
                                                   float* __restrict__ feats) {
    __shared__ float hrow[4 * H_];
    int tid = threadIdx.x;
    int base = blockIdx.x * 4;
    for (int idx = tid; idx < 4 * H_; idx += 256)
        hrow[idx] = lstm_out[(long)base * H_ + idx];
    __syncthreads();
    int il = tid >> 6, s = tid & 63;
    if (s < S_) {
        float acc = btag[s];
        const float* hr = hrow + il * H_;
#pragma unroll 4
        for (int k = 0; k < H_; ++k)
            acc = fmaf(hr[k], wtagT[k * S_ + s], acc);
        feats[(base + il) * S_ + s] = acc;
    }
}

// ---------------- CRF forward + labeled score. Block=batch, 512 thr: j=tid>>3, 8 lanes/j.
__global__ __launch_bounds__(512) void crf_kernel(const float* __restrict__ feats,
                                                  const float* __restrict__ trans,
                                                  const int* __restrict__ tags,
                                                  const int* __restrict__ seqlens,
                                                  float* __restrict__ acc) {
    __shared__ float Tt[S_ * S_];   // Tt[j*50+i] = trans[i*50+j]
    __shared__ float alpha[S_];
    __shared__ float lastal[S_];
    __shared__ int tg[L_];
    int tid = threadIdx.x;
    int b = blockIdx.x;
    for (int idx = tid; idx < S_ * S_; idx += 512) {
        int j = idx / S_, i = idx % S_;
        Tt[idx] = trans[i * S_ + j];
    }
    if (tid < L_) tg[tid] = tags[b * L_ + tid];
    int slen = seqlens[b];
    const float* fb = feats + (long)b * L_ * S_;
    __syncthreads();
    if (tid < S_) {
        float a = Tt[tid * S_ + START_] + fb[tid];
        alpha[tid] = a;
        if (slen == 1) lastal[tid] = a;
    }
    __syncthreads();
    int j = tid >> 3, sub = tid & 7;
    bool jact = j < S_;
    for (int t = 1; t < L_; ++t) {
        float anew = 0.f;
        if (jact) {
            float m = -1e30f;
            for (int i = sub; i < S_; i += 8) m = fmaxf(m, alpha[i] + Tt[j * S_ + i]);
            m = fmaxf(m, __shfl_xor(m, 1));
            m = fmaxf(m, __shfl_xor(m, 2));
            m = fmaxf(m, __shfl_xor(m, 4));
            float s = 0.f;
            for (int i = sub; i < S_; i += 8) s += __expf(alpha[i] + Tt[j * S_ + i] - m);
            s += __shfl_xor(s, 1);
            s += __shfl_xor(s, 2);
            s += __shfl_xor(s, 4);
            anew = m + __logf(s) + fb[t * S_ + j];
        }
        __syncthreads();
        if (jact && sub == 0) {
            alpha[j] = anew;
            if (t == slen - 1) lastal[j] = anew;
        }
        __syncthreads();
    }
    if (tid < 64) {
        float la = (tid < S_) ? (lastal[tid] + Tt[END_ * S_ + tid]) : -1e30f;
        float m = la;
        for (int off = 32; off; off >>= 1) m = fmaxf(m, __shfl_xor(m, off));
        float e = (tid < S_) ? __expf(la - m) : 0.f;
        for (int off = 32; off; off >>= 1) e += __shfl_xor(e, off);
        float unl = m + __logf(e);
        float lab = 0.f;
        for (int tt = tid; tt < L_; tt += 64) {
            if (tt == 0) {
                lab += Tt[tg[0] * S_ + START_] + fb[tg[0]];
            } else if (tt < slen) {
                lab += Tt[tg[tt] * S_ + tg[tt - 1]] + fb[tt * S_ + tg[tt]];
            }
        }
        if (tid == 0) lab += Tt[END_ * S_ + tg[slen - 1]];
        for (int off = 32; off; off >>= 1) lab += __shfl_xor(lab, off);
        if (tid == 0) atomicAdd(acc, unl - lab);
    }
}

__global__ void fin_kernel(const float* __restrict__ acc, float* __restrict__ out) {
    out[0] = acc[0];
}

extern "C" void kernel_launch(void* const* d_in, const int* in_sizes, int n_in,
                              void* d_out, int out_size, void* d_ws, size_t ws_size,
                              hipStream_t stream) {
    const int*   words = (const int*)d_in[0];
    const int*   slens = (const int*)d_in[1];
    // d_in[2] = masks: semantically (t < seq_len); not read.
    const int*   tags  = (const int*)d_in[3];
    const float* emb   = (const float*)d_in[4];
    const float* wihf  = (const float*)d_in[5];
    const float* whhf  = (const float*)d_in[6];
    const float* bf    = (const float*)d_in[7];
    const float* wihb  = (const float*)d_in[8];
    const float* whhb  = (const float*)d_in[9];
    const float* bb    = (const float*)d_in[10];
    const float* wtag  = (const float*)d_in[11];
    const float* btag  = (const float*)d_in[12];
    const float* trans = (const float*)d_in[13];

    char* ws = (char*)d_ws;
    unsigned short* xg   = (unsigned short*)(ws + OFF_XG);
    float*          lstm = (float*)(ws + OFF_LSTM);
    uint4*          w16q = (uint4*)(ws + OFF_SH);   // prep -> lstm
    float*          fts  = (float*)(ws + OFF_SH);   // feat -> crf (time-shared)
    float*          wtT  = (float*)(ws + OFF_WTT);
    float*          accb = (float*)(ws + OFF_ACC);
    float*          out  = (float*)d_out;

    prep_kernel<<<157, 256, 0, stream>>>(whhf, whhb, wtag, wtT, w16q, accb);
    xg_gemm<<<dim3(13, 64), 256, 0, stream>>>(words, emb, wihf, wihb, bf, bb, xg);
    lstm_rec<<<128, 512, 0, stream>>>(xg, w16q, lstm);
    feat_kernel<<<2048, 256, 0, stream>>>(lstm, wtT, btag, fts);
    crf_kernel<<<64, 512, 0, stream>>>(fts, trans, tags, slens, accb);
    fin_kernel<<<1, 1, 0, stream>>>(accb, out);
}

// Round 4
// 467.030 us; speedup vs baseline: 8.1463x; 8.1463x over previous
//
#include <hip/hip_runtime.h>
#include <hip/hip_fp16.h>

#define B_ 64
#define L_ 128
#define E_ 300
#define HD_ 200
#define H_ 400
#define S_ 50
#define START_ 48
#define END_ 49
#define NG_ 1600
#define BL_ 8192

// ---- ws layout (bytes) ----
// OFF_SH region is time-shared: w16q (prep->lstm), then feats (feat->crf).
#define OFF_XG   0ull                         // bf16 [8192][1600]  26,214,400
#define OFF_LSTM (OFF_XG + 26214400ull)       // f32  [8192][400]   13,107,200
#define OFF_SH   (OFF_LSTM + 13107200ull)     // max(w16q 640,000 ; feats 1,638,400)
#define OFF_WTT  (OFF_SH + 1638400ull)        // f32  [400][50]     80,000
#define OFF_ACC  (OFF_WTT + 80000ull)         // f32  [1]

typedef __attribute__((ext_vector_type(8))) short short8;
typedef __attribute__((ext_vector_type(4))) float f32x4;
typedef _Float16 h2v __attribute__((ext_vector_type(2)));

__device__ __forceinline__ unsigned short f32_to_bf16(float f) {
    unsigned u = __float_as_uint(f);
    unsigned r = u + 0x7fffu + ((u >> 16) & 1u);
    return (unsigned short)(r >> 16);
}
__device__ __forceinline__ float bf16_to_f32(unsigned short s) {
    return __uint_as_float(((unsigned)s) << 16);
}
__device__ __forceinline__ unsigned packh2(float a, float b) {
    return (unsigned)__half_as_ushort(__float2half(a)) |
           ((unsigned)__half_as_ushort(__float2half(b)) << 16);
}
__device__ __forceinline__ float hlo(unsigned u) {
    return __half2float(__ushort_as_half((unsigned short)(u & 0xffffu)));
}
__device__ __forceinline__ float hhi(unsigned u) {
    return __half2float(__ushort_as_half((unsigned short)(u >> 16)));
}
// 2-wide f16 dot with f32 accumulate: v_dot2_f32_f16 (fallback: cvt+fma).
__device__ __forceinline__ float fdot2(unsigned w, unsigned h, float c) {
#if __has_builtin(__builtin_amdgcn_fdot2)
    return __builtin_amdgcn_fdot2(__builtin_bit_cast(h2v, w), __builtin_bit_cast(h2v, h), c, false);
#else
    c = fmaf(hlo(w), hlo(h), c);
    return fmaf(hhi(w), hhi(h), c);
#endif
}

// ---------------- prep: w_hh (both dirs) -> f16x2 uint4 [dir][kq(25)][row(800)];
// W_tag transpose; acc=0.  word(kq,row) packs w[row][8kq..8kq+7].
__global__ void prep_kernel(const float* __restrict__ whh_f, const float* __restrict__ whh_b,
                            const float* __restrict__ wtag, float* __restrict__ wtagT,
                            uint4* __restrict__ w16q, float* __restrict__ acc) {
    int g = blockIdx.x * 256 + threadIdx.x;
    if (g < 40000) {
        int dir = g / 20000;
        int r = g % 20000;
        int kq = r / 800;
        int row = r % 800;
        const float* w = dir ? whh_b : whh_f;
        const float* src = w + row * HD_ + 8 * kq;
        uint4 o;
        o.x = packh2(src[0], src[1]);
        o.y = packh2(src[2], src[3]);
        o.z = packh2(src[4], src[5]);
        o.w = packh2(src[6], src[7]);
        w16q[g] = o;
    }
    if (g < 20000) {
        int k = g / S_, s = g % S_;
        wtagT[g] = wtag[s * H_ + k];
    }
    if (g == 0) acc[0] = 0.f;
}

// ---------------- xg GEMM (MFMA bf16): unchanged (passes, not yet the bottleneck).
__global__ __launch_bounds__(256) void xg_gemm(const int* __restrict__ words,
                                               const float* __restrict__ emb,
                                               const float* __restrict__ wihf,
                                               const float* __restrict__ wihb,
                                               const float* __restrict__ bfc,
                                               const float* __restrict__ bbc,
                                               unsigned short* __restrict__ xg) {
    __shared__ unsigned short As[128 * 40];
    __shared__ unsigned short Bs[128 * 40];
    __shared__ int wlds[128];
    int tid = threadIdx.x;
    int bm = blockIdx.y * 128;
    int bn = blockIdx.x * 128;
    if (tid < 128) wlds[tid] = words[bm + tid];
    __syncthreads();

    int srow = tid >> 1;
    int ks = (tid & 1) * 16;
    int lane = tid & 63;
    int wave = tid >> 6;
    int r16 = lane & 15;
    int kh = lane >> 4;

    f32x4 acc[2][8];
#pragma unroll
    for (int mi = 0; mi < 2; ++mi)
#pragma unroll
        for (int ni = 0; ni < 8; ++ni) acc[mi][ni] = (f32x4){0.f, 0.f, 0.f, 0.f};

    const float* arow = emb + (long)wlds[srow] * E_;
    int gB = bn + srow;
    const float* brow = (gB < 800) ? (wihf + (long)gB * E_) : (wihb + (long)(gB - 800) * E_);
    bool bvalid = gB < NG_;

    for (int k0 = 0; k0 < 320; k0 += 32) {
#pragma unroll
        for (int j = 0; j < 4; ++j) {
            int k = k0 + ks + 4 * j;
            float4 va = (k < E_) ? *(const float4*)(arow + k) : make_float4(0.f, 0.f, 0.f, 0.f);
            unsigned p0 = (unsigned)f32_to_bf16(va.x) | ((unsigned)f32_to_bf16(va.y) << 16);
            unsigned p1 = (unsigned)f32_to_bf16(va.z) | ((unsigned)f32_to_bf16(va.w) << 16);
            *(uint2*)&As[srow * 40 + ks + 4 * j] = make_uint2(p0, p1);
            float4 vb = (bvalid && k < E_) ? *(const float4*)(brow + k) : make_float4(0.f, 0.f, 0.f, 0.f);
            unsigned q0 = (unsigned)f32_to_bf16(vb.x) | ((unsigned)f32_to_bf16(vb.y) << 16);
            unsigned q1 = (unsigned)f32_to_bf16(vb.z) | ((unsigned)f32_to_bf16(vb.w) << 16);
            *(uint2*)&Bs[srow * 40 + ks + 4 * j] = make_uint2(q0, q1);
        }
        __syncthreads();
        short8 af[2], bfv[8];
#pragma unroll
        for (int mi = 0; mi < 2; ++mi)
            af[mi] = *(const short8*)&As[(wave * 32 + mi * 16 + r16) * 40 + kh * 8];
#pragma unroll
        for (int ni = 0; ni < 8; ++ni)
            bfv[ni] = *(const short8*)&Bs[(ni * 16 + r16) * 40 + kh * 8];
#pragma unroll
        for (int mi = 0; mi < 2; ++mi)
#pragma unroll
            for (int ni = 0; ni < 8; ++ni)
                acc[mi][ni] = __builtin_amdgcn_mfma_f32_16x16x32_bf16(af[mi], bfv[ni], acc[mi][ni], 0, 0, 0);
        __syncthreads();
    }
#pragma unroll
    for (int ni = 0; ni < 8; ++ni) {
        int g = bn + ni * 16 + r16;
        if (g < NG_) {
            float bias = (g < 800) ? bfc[g] : bbc[g - 800];
#pragma unroll
            for (int mi = 0; mi < 2; ++mi) {
#pragma unroll
                for (int r = 0; r < 4; ++r) {
                    int row = bm + wave * 32 + mi * 16 + kh * 4 + r;
                    xg[(long)row * NG_ + g] = f32_to_bf16(acc[mi][ni][r] + bias);
                }
            }
        }
    }
}

// ---------------- LSTM recurrence: block=(dir,batch), 512 thr, __launch_bounds__(512,2)
// => min 2 waves/EU => VGPR cap 256 (round-3 failed at the default cap 128).
// Thread t<400 owns gate rows {t, t+400}: 2x25 uint4 f16 weights = 200 VGPR, register-resident.
// h kept in LDS as PACKED f16; inner loop = 200 v_dot2_f32_f16 per thread per step.
__global__ __launch_bounds__(512, 2) void lstm_rec(const unsigned short* __restrict__ xg,
                                                   const uint4* __restrict__ w16q,
                                                   float* __restrict__ lstm_out) {
    __shared__ __align__(16) unsigned short h16[HD_];   // packed f16 h
    __shared__ float a_lds[2 * HD_];                    // [0:200)=sig(f), [200:400)=sig(o)
    int tid = threadIdx.x;
    int dir = blockIdx.x >> 6;
    int b = blockIdx.x & 63;
    bool act = tid < 400;

    uint4 wA[25], wB[25];
    const uint4* wp = w16q + dir * 20000;
    if (act) {
#pragma unroll
        for (int kq = 0; kq < 25; ++kq) {
            wA[kq] = wp[kq * 800 + tid];
            wB[kq] = wp[kq * 800 + tid + 400];
        }
    }
    if (tid < HD_) h16[tid] = 0;
    float c = 0.f;
    __syncthreads();
    const uint4* h4 = (const uint4*)h16;
    const unsigned short* xbase = xg + (long)b * L_ * NG_ + dir * 800;

    int t0 = dir ? (L_ - 1) : 0;
    float xa = act ? bf16_to_f32(xbase[(long)t0 * NG_ + tid]) : 0.f;
    float xb = act ? bf16_to_f32(xbase[(long)t0 * NG_ + tid + 400]) : 0.f;

    for (int step = 0; step < L_; ++step) {
        int t = dir ? (L_ - 1 - step) : step;
        // prefetch next step's x (hides L2 latency under the dot2 chain)
        float xa_n = 0.f, xb_n = 0.f;
        if (act && step + 1 < L_) {
            int tn = dir ? (t - 1) : (t + 1);
            xa_n = bf16_to_f32(xbase[(long)tn * NG_ + tid]);
            xb_n = bf16_to_f32(xbase[(long)tn * NG_ + tid + 400]);
        }
        float pa = 0.f, pb = 0.f;
        if (act) {
            float sa0 = xa, sa1 = 0.f, sb0 = xb, sb1 = 0.f;
#pragma unroll
            for (int kq = 0; kq < 25; ++kq) {
                uint4 hv = h4[kq];
                uint4 a = wA[kq];
                uint4 w2 = wB[kq];
                sa0 = fdot2(a.x, hv.x, sa0); sa1 = fdot2(a.y, hv.y, sa1);
                sa0 = fdot2(a.z, hv.z, sa0); sa1 = fdot2(a.w, hv.w, sa1);
                sb0 = fdot2(w2.x, hv.x, sb0); sb1 = fdot2(w2.y, hv.y, sb1);
                sb0 = fdot2(w2.z, hv.z, sb0); sb1 = fdot2(w2.w, hv.w, sb1);
            }
            pa = sa0 + sa1;
            pb = sb0 + sb1;
            if (tid >= 200) {
                a_lds[tid - 200] = 1.f / (1.f + __expf(-pa));   // sig(f) at [ko]
                a_lds[tid]       = 1.f / (1.f + __expf(-pb));   // sig(o) at [200+ko]
            }
        }
        __syncthreads();
        if (tid < HD_) {
            float ig = 1.f / (1.f + __expf(-pa));
            float e2 = __expf(-2.f * pb);
            float gg = 2.f / (1.f + e2) - 1.f;                  // tanh(g~)
            float fg = a_lds[tid];
            float og = a_lds[200 + tid];
            c = fg * c + ig * gg;
            float ec = __expf(-2.f * c);
            float hn = og * (2.f / (1.f + ec) - 1.f);
            h16[tid] = (unsigned short)__half_as_ushort(__float2half(hn));
            lstm_out[((long)(b * L_ + t)) * H_ + dir * HD_ + tid] = hn;
        }
        xa = xa_n; xb = xb_n;
        __syncthreads();
    }
}

// ---------------- features = lstm_out @ W_tag^T + b_tag
__global__ __launch_bounds__(256) void feat_kernel(const float* __restrict__ lstm_out,
                                                   const float* __restrict__ wtagT,
                                                   const float* __restrict__ btag,
                                                   float* __restrict__ feats) {
    __shared__ float hrow[4 * H_];
    int tid = threadIdx.x;
    int base = blockIdx.x * 4;
    for (int idx = tid; idx < 4 * H_; idx += 256)
        hrow[idx] = lstm_out[(long)base * H_ + idx];
    __syncthreads();
    int il = tid >> 6, s = tid & 63;
    if (s < S_) {
        float acc = btag[s];
        const float* hr = hrow + il * H_;
#pragma unroll 4
        for (int k = 0; k < H_; ++k)
            acc = fmaf(hr[k], wtagT[k * S_ + s], acc);
        feats[(base + il) * S_ + s] = acc;
    }
}

// ---------------- CRF forward + labeled score. Block=batch, 512 thr: j=tid>>3, 8 lanes/j.
__global__ __launch_bounds__(512) void crf_kernel(const float* __restrict__ feats,
                                                  const float* __restrict__ trans,
                                                  const int* __restrict__ tags,
                                                  const int* __restrict__ seqlens,
                                                  float* __restrict__ acc) {
    __shared__ float Tt[S_ * S_];   // Tt[j*50+i] = trans[i*50+j]
    __shared__ float alpha[S_];
    __shared__ float lastal[S_];
    __shared__ int tg[L_];
    int tid = threadIdx.x;
    int b = blockIdx.x;
    for (int idx = tid; idx < S_ * S_; idx += 512) {
        int j = idx / S_, i = idx % S_;
        Tt[idx] = trans[i * S_ + j];
    }
    if (tid < L_) tg[tid] = tags[b * L_ + tid];
    int slen = seqlens[b];
    const float* fb = feats + (long)b * L_ * S_;
    __syncthreads();
    if (tid < S_) {
        float a = Tt[tid * S_ + START_] + fb[tid];
        alpha[tid] = a;
        if (slen == 1) lastal[tid] = a;
    }
    __syncthreads();
    int j = tid >> 3, sub = tid & 7;
    bool jact = j < S_;
    for (int t = 1; t < L_; ++t) {
        float anew = 0.f;
        if (jact) {
            float m = -1e30f;
            for (int i = sub; i < S_; i += 8) m = fmaxf(m, alpha[i] + Tt[j * S_ + i]);
            m = fmaxf(m, __shfl_xor(m, 1));
            m = fmaxf(m, __shfl_xor(m, 2));
            m = fmaxf(m, __shfl_xor(m, 4));
            float s = 0.f;
            for (int i = sub; i < S_; i += 8) s += __expf(alpha[i] + Tt[j * S_ + i] - m);
            s += __shfl_xor(s, 1);
            s += __shfl_xor(s, 2);
            s += __shfl_xor(s, 4);
            anew = m + __logf(s) + fb[t * S_ + j];
        }
        __syncthreads();
        if (jact && sub == 0) {
            alpha[j] = anew;
            if (t == slen - 1) lastal[j] = anew;
        }
        __syncthreads();
    }
    if (tid < 64) {
        float la = (tid < S_) ? (lastal[tid] + Tt[END_ * S_ + tid]) : -1e30f;
        float m = la;
        for (int off = 32; off; off >>= 1) m = fmaxf(m, __shfl_xor(m, off));
        float e = (tid < S_) ? __expf(la - m) : 0.f;
        for (int off = 32; off; off >>= 1) e += __shfl_xor(e, off);
        float unl = m + __logf(e);
        float lab = 0.f;
        for (int tt = tid; tt < L_; tt += 64) {
            if (tt == 0) {
                lab += Tt[tg[0] * S_ + START_] + fb[tg[0]];
            } else if (tt < slen) {
                lab += Tt[tg[tt] * S_ + tg[tt - 1]] + fb[tt * S_ + tg[tt]];
            }
        }
        if (tid == 0) lab += Tt[END_ * S_ + tg[slen - 1]];
        for (int off = 32; off; off >>= 1) lab += __shfl_xor(lab, off);
        if (tid == 0) atomicAdd(acc, unl - lab);
    }
}

__global__ void fin_kernel(const float* __restrict__ acc, float* __restrict__ out) {
    out[0] = acc[0];
}

extern "C" void kernel_launch(void* const* d_in, const int* in_sizes, int n_in,
                              void* d_out, int out_size, void* d_ws, size_t ws_size,
                              hipStream_t stream) {
    const int*   words = (const int*)d_in[0];
    const int*   slens = (const int*)d_in[1];
    // d_in[2] = masks: semantically (t < seq_len); not read.
    const int*   tags  = (const int*)d_in[3];
    const float* emb   = (const float*)d_in[4];
    const float* wihf  = (const float*)d_in[5];
    const float* whhf  = (const float*)d_in[6];
    const float* bf    = (const float*)d_in[7];
    const float* wihb  = (const float*)d_in[8];
    const float* whhb  = (const float*)d_in[9];
    const float* bb    = (const float*)d_in[10];
    const float* wtag  = (const float*)d_in[11];
    const float* btag  = (const float*)d_in[12];
    const float* trans = (const float*)d_in[13];

    char* ws = (char*)d_ws;
    unsigned short* xg   = (unsigned short*)(ws + OFF_XG);
    float*          lstm = (float*)(ws + OFF_LSTM);
    uint4*          w16q = (uint4*)(ws + OFF_SH);   // prep -> lstm
    float*          fts  = (float*)(ws + OFF_SH);   // feat -> crf (time-shared)
    float*          wtT  = (float*)(ws + OFF_WTT);
    float*          accb = (float*)(ws + OFF_ACC);
    float*          out  = (float*)d_out;

    prep_kernel<<<157, 256, 0, stream>>>(whhf, whhb, wtag, wtT, w16q, accb);
    xg_gemm<<<dim3(13, 64), 256, 0, stream>>>(words, emb, wihf, wihb, bf, bb, xg);
    lstm_rec<<<128, 512, 0, stream>>>(xg, w16q, lstm);
    feat_kernel<<<2048, 256, 0, stream>>>(lstm, wtT, btag, fts);
    crf_kernel<<<64, 512, 0, stream>>>(fts, trans, tags, slens, accb);
    fin_kernel<<<1, 1, 0, stream>>>(accb, out);
}